// Round 2
// baseline (189.063 us; speedup 1.0000x reference)
//
#include <hip/hip_runtime.h>
#include <math.h>

// ws layout (floats)
#define WS_H     0
#define WS_U     128
#define WS_W2    256
#define WS_QBK   384
#define WS_S0    385
#define WS_S1    386
#define WS_GUARD 400
#define WS_ACCR  512          // NREP replicas of [2048 acc | 16 esum]
#define REP_STRIDE 2064
#define NREP 4

__device__ __forceinline__ float frcp_(float x){ return __builtin_amdgcn_rcpf(x); }
__device__ __forceinline__ float fsig_(float x){ return frcp_(1.f + __expf(-x)); }
__device__ __forceinline__ float ftanh_(float x){ return 1.f - 2.f*frcp_(1.f + __expf(2.f*x)); }

// ---------------- K0: per-XCD L2 prefetch of all weights + ws init ----------------
__device__ __forceinline__ float pf_(const float* __restrict__ p, int n, int part, int tid) {
    const int per4 = n >> 7;                        // float4s per 1/32 slice
    const float4* p4 = (const float4*)p + part * per4;
    float a = 0.f;
    for (int i = tid; i < per4; i += 256) { float4 v = p4[i]; a += v.x + v.y + v.z + v.w; }
    return a;
}

__global__ __launch_bounds__(256) void k0_prefetch(
    const float* __restrict__ W_ih, const float* __restrict__ W_hh,
    const float* __restrict__ Wq,  const float* __restrict__ Wk,
    const float* __restrict__ Wv,  const float* __restrict__ Wo,
    const float* __restrict__ Wgq, const float* __restrict__ Wgk,
    const float* __restrict__ Wgv, const float* __restrict__ Wc,
    float* __restrict__ ws)
{
    const int tid = threadIdx.x;
    const int bid = blockIdx.x;
    if (bid == 0) {
        for (int i = tid; i < NREP * REP_STRIDE; i += 256) ws[WS_ACCR + i] = 0.f;
    }
    const int part = bid >> 3;                      // 32 slices × 8 XCD copies
    float a = pf_(W_hh, 65536, part, tid);
    a += pf_(W_ih, 4096,  part, tid);
    a += pf_(Wq,  16384, part, tid);
    a += pf_(Wk,  16384, part, tid);
    a += pf_(Wv,  16384, part, tid);
    a += pf_(Wo,  16384, part, tid);
    a += pf_(Wgq, 16384, part, tid);
    a += pf_(Wgk, 16384, part, tid);
    a += pf_(Wgv, 16384, part, tid);
    if (part < 2) a += pf_(Wc, 256, part, tid);
    if (a == 1.0e38f) ws[WS_GUARD] = a;             // never true; keeps loads live
}

// ---------------- K1: serial target LSTM + folded precomputes ----------------
__global__ __launch_bounds__(512, 2) void k1_target(
    const float* __restrict__ target,
    const float* __restrict__ W_ih, const float* __restrict__ W_hh,
    const float* __restrict__ b_ih, const float* __restrict__ b_hh,
    const float* __restrict__ Wq,  const float* __restrict__ bq,
    const float* __restrict__ Wk,  const float* __restrict__ bk,
    const float* __restrict__ Wv,  const float* __restrict__ bv,
    const float* __restrict__ Wo,  const float* __restrict__ bo,
    const float* __restrict__ Wgq, const float* __restrict__ bgq,
    const float* __restrict__ Wgk, const float* __restrict__ bgk,
    float* __restrict__ ws)
{
    __shared__ __align__(16) float h_s[128];
    __shared__ float g_s[512];
    __shared__ float red[512];
    __shared__ __align__(16) float qq_s[256];       // q | qg
    __shared__ __align__(16) float u_s[128], ug_s[128], w1_s[128], w2_s[128];
    const int tid = threadIdx.x;
    if (tid < 128) h_s[tid] = 0.f;

    float wih[8];
    #pragma unroll
    for (int k = 0; k < 8; ++k) wih[k] = W_ih[tid*8 + k];
    const float bsum = b_ih[tid] + b_hh[tid];
    float4 whh[32];                                  // 128 VGPRs, resident (launch_bounds 512,2)
    {
        const float4* w4 = (const float4*)(W_hh + tid*128);
        #pragma unroll
        for (int m = 0; m < 32; ++m) whh[m] = w4[m];
    }
    float c = 0.f;
    __syncthreads();

    for (int t = 0; t < 15; ++t) {
        float g = bsum;
        #pragma unroll
        for (int k = 0; k < 8; ++k) g += target[t*8 + k] * wih[k];
        const float4* h4 = (const float4*)h_s;
        float a0 = 0.f, a1 = 0.f, a2 = 0.f, a3 = 0.f;
        #pragma unroll
        for (int m = 0; m < 32; m += 4) {
            float4 x0 = h4[m], x1 = h4[m+1], x2 = h4[m+2], x3 = h4[m+3];
            a0 += whh[m  ].x*x0.x + whh[m  ].y*x0.y + whh[m  ].z*x0.z + whh[m  ].w*x0.w;
            a1 += whh[m+1].x*x1.x + whh[m+1].y*x1.y + whh[m+1].z*x1.z + whh[m+1].w*x1.w;
            a2 += whh[m+2].x*x2.x + whh[m+2].y*x2.y + whh[m+2].z*x2.z + whh[m+2].w*x2.w;
            a3 += whh[m+3].x*x3.x + whh[m+3].y*x3.y + whh[m+3].z*x3.z + whh[m+3].w*x3.w;
        }
        g += (a0 + a1) + (a2 + a3);
        g_s[tid] = g;
        __syncthreads();
        if (tid < 128) {
            float ig = fsig_(g_s[tid]);
            float fg = fsig_(g_s[tid+128]);
            float gg = ftanh_(g_s[tid+256]);
            float og = fsig_(g_s[tid+384]);
            c = fg*c + ig*gg;
            h_s[tid] = og*ftanh_(c);
        }
        __syncthreads();
    }

    // phase A: q = Wq h + bq (o<128), qg = Wgq h + bgq (o>=128); 2-way j-split
    {
        const int o = tid & 255, p = tid >> 8;
        const float* Wrow = (o < 128) ? (Wq + o*128) : (Wgq + (o & 127)*128);
        const float4* w4 = (const float4*)Wrow + p*16;
        const float4* h4 = (const float4*)h_s + p*16;
        float a = 0.f;
        #pragma unroll
        for (int m = 0; m < 16; ++m) { float4 w = w4[m], v = h4[m];
            a += w.x*v.x + w.y*v.y + w.z*v.z + w.w*v.w; }
        red[tid] = a;
    }
    __syncthreads();
    if (tid < 256) qq_s[tid] = red[tid] + red[tid+256] + ((tid < 128) ? bq[tid] : bgq[tid & 127]);
    __syncthreads();
    // phase B: u = Wk^T q (o<128), ug = Wgk^T qg; coalesced, 2-way j-split
    {
        const int o = tid & 255, p = tid >> 8;
        const int a_ = o & 127;
        const float* W = (o < 128) ? Wk : Wgk;
        const int qb = (o < 128) ? 0 : 128;
        float a = 0.f;
        #pragma unroll 8
        for (int j = p*64; j < p*64 + 64; ++j) a += qq_s[qb + j] * W[j*128 + a_];
        red[tid] = a;
    }
    __syncthreads();
    if (tid < 256) {
        float v = red[tid] + red[tid+256];
        if (tid < 128) u_s[tid] = v; else ug_s[tid & 127] = v;
    }
    __syncthreads();
    // phase C: w1 = Wo^T ug; 4-way j-split
    {
        const int o = tid & 127, p = tid >> 7;
        float a = 0.f;
        #pragma unroll 8
        for (int j = p*32; j < p*32 + 32; ++j) a += ug_s[j] * Wo[j*128 + o];
        red[tid] = a;
    }
    __syncthreads();
    if (tid < 128) w1_s[tid] = red[tid] + red[tid+128] + red[tid+256] + red[tid+384];
    __syncthreads();
    // phase D: w2 = Wv^T w1; 4-way j-split
    {
        const int o = tid & 127, p = tid >> 7;
        float a = 0.f;
        #pragma unroll 8
        for (int j = p*32; j < p*32 + 32; ++j) a += w1_s[j] * Wv[j*128 + o];
        red[tid] = a;
    }
    __syncthreads();
    if (tid < 128) w2_s[tid] = red[tid] + red[tid+128] + red[tid+256] + red[tid+384];
    __syncthreads();
    if (tid < 128) {
        red[tid]     = qq_s[tid] * bk[tid];
        red[128+tid] = qq_s[128+tid] * bgk[tid];
        red[256+tid] = w1_s[tid]*bv[tid] + ug_s[tid]*bo[tid];
    }
    __syncthreads();
    if (tid == 0) {
        float qbk = 0.f, s0 = 0.f, sx = 0.f;
        for (int j = 0; j < 128; ++j) { qbk += red[j]; s0 += red[128+j]; sx += red[256+j]; }
        ws[WS_QBK] = qbk; ws[WS_S0] = s0; ws[WS_S1] = sx + s0;
    }
    if (tid < 128) {
        ws[WS_H + tid]  = h_s[tid];
        ws[WS_U + tid]  = u_s[tid];
        ws[WS_W2 + tid] = w2_s[tid];
    }
}

// ---------------- K3: neighbor pass (t=14 only), wave-per-neighbor ----------------
#define K3_BLOCKS 64
__global__ __launch_bounds__(256) void k3_neighbors(
    const float* __restrict__ target, const float* __restrict__ others,
    const int* __restrict__ mask, const float* __restrict__ W_ih,
    const float* __restrict__ b_ih, const float* __restrict__ b_hh,
    float* __restrict__ ws)
{
    __shared__ float accs[16*128];
    __shared__ float esums[16];
    __shared__ int used[16];
    const int tid  = threadIdx.x;
    const int lane = tid & 63;
    const int wave = tid >> 6;

    for (int i = tid; i < 2048; i += 256) accs[i] = 0.f;
    if (tid < 16) { esums[tid] = 0.f; used[tid] = 0; }

    const int d0 = lane, d1 = lane + 64;
    float wi0[8], wg0[8], wo0[8], wi1[8], wg1[8], wo1[8];
    #pragma unroll
    for (int k = 0; k < 8; ++k) {
        wi0[k] = W_ih[d0*8+k];        wi1[k] = W_ih[d1*8+k];
        wg0[k] = W_ih[(256+d0)*8+k];  wg1[k] = W_ih[(256+d1)*8+k];
        wo0[k] = W_ih[(384+d0)*8+k];  wo1[k] = W_ih[(384+d1)*8+k];
    }
    const float bi0 = b_ih[d0]+b_hh[d0],         bi1 = b_ih[d1]+b_hh[d1];
    const float bg0 = b_ih[256+d0]+b_hh[256+d0], bg1 = b_ih[256+d1]+b_hh[256+d1];
    const float bo0 = b_ih[384+d0]+b_hh[384+d0], bo1 = b_ih[384+d1]+b_hh[384+d1];
    const float u0 = ws[WS_U + d0], u1 = ws[WS_U + d1];
    const float qbk = ws[WS_QBK];
    const float tx0 = target[14*8 + 0], tx1 = target[14*8 + 1];
    const float* __restrict__ oth  = others + 14*16384*8;
    const int*   __restrict__ mk14 = mask   + 14*16384;
    const float scale = 0.08838834764831845f;  // 1/sqrt(128)
    __syncthreads();

    const int gw = blockIdx.x*4 + wave;                   // [0,256)
    const int nper = 16384 / (K3_BLOCKS*4);               // 64
    for (int n = gw*nper; n < gw*nper + nper; ++n) {
        const int mk = mk14[n];
        const float4 xa = ((const float4*)oth)[n*2];
        const float4 xb = ((const float4*)oth)[n*2 + 1];
        const float r0 = xa.x - tx0, r1 = xa.y - tx1;
        bool ok = (fabsf(r0) <= 2.f) & (fabsf(r1) <= 2.f) & (mk != 0);
        const int cx = (int)truncf(r0) + 2;               // cw = ch = 1.0 exactly
        const int cy = (int)truncf(r1) + 2;
        ok = ok & (cx >= 0) & (cx < 4) & (cy >= 0) & (cy < 4);
        if (!ok) continue;                                // wave-uniform predicate
        const int cell = cy*4 + cx;
        float x[8] = {xa.x, xa.y, xa.z, xa.w, xb.x, xb.y, xb.z, xb.w};
        float gi = bi0, gg = bg0, go = bo0;
        #pragma unroll
        for (int k = 0; k < 8; ++k) { gi += x[k]*wi0[k]; gg += x[k]*wg0[k]; go += x[k]*wo0[k]; }
        const float ho0 = fsig_(go) * ftanh_(fsig_(gi) * ftanh_(gg));
        gi = bi1; gg = bg1; go = bo1;
        #pragma unroll
        for (int k = 0; k < 8; ++k) { gi += x[k]*wi1[k]; gg += x[k]*wg1[k]; go += x[k]*wo1[k]; }
        const float ho1 = fsig_(go) * ftanh_(fsig_(gi) * ftanh_(gg));
        float p = u0*ho0 + u1*ho1;
        #pragma unroll
        for (int s = 1; s < 64; s <<= 1) p += __shfl_xor(p, s, 64);
        const float sc = (p + qbk) * scale;
        const float e = __expf(sc);   // per-cell max subtraction is softmax-invariant; |sc| << 1
        atomicAdd(&accs[cell*128 + d0], e*ho0);
        atomicAdd(&accs[cell*128 + d1], e*ho1);
        if (lane == 0) { atomicAdd(&esums[cell], e); used[cell] = 1; }
    }
    __syncthreads();
    const int rep = blockIdx.x & (NREP-1);
    float* wacc = ws + WS_ACCR + rep*REP_STRIDE;
    for (int i = tid; i < 2048; i += 256) {
        const int c = i >> 7;
        if (used[c]) {
            const float v = accs[i];
            if (v != 0.f) atomicAdd(&wacc[i], v);
        }
    }
    if (tid < 16 && used[tid]) atomicAdd(&wacc[2048 + tid], esums[tid]);
}

// ---------------- K4: finale (grid attention folded to matvecs) ----------------
__global__ __launch_bounds__(128) void k4_finale(
    const float* __restrict__ Wv, const float* __restrict__ bv,
    const float* __restrict__ Wo, const float* __restrict__ bo,
    const float* __restrict__ Wgv, const float* __restrict__ bgv,
    const float* __restrict__ Wc, const float* __restrict__ bc,
    const float* __restrict__ ws, float* __restrict__ out)
{
    __shared__ __align__(16) float avg[16*128];
    __shared__ float es_s[16];
    __shared__ float gw_s[16];
    __shared__ float s_sh[16];
    __shared__ __align__(16) float mavg[128], t_s[128], mix[128], comb[128];
    __shared__ float alpha_s;
    const int tid = threadIdx.x;
    const float scale = 0.08838834764831845f;

    if (tid < 16) {
        float e = 0.f;
        #pragma unroll
        for (int r = 0; r < NREP; ++r) e += ws[WS_ACCR + r*REP_STRIDE + 2048 + tid];
        es_s[tid] = e;
    }
    __syncthreads();
    #pragma unroll
    for (int c = 0; c < 16; ++c) {
        float a = 0.f;
        #pragma unroll
        for (int r = 0; r < NREP; ++r) a += ws[WS_ACCR + r*REP_STRIDE + c*128 + tid];
        avg[c*128 + tid] = (es_s[c] > 0.f) ? a / es_s[c] : 0.f;
    }
    __syncthreads();
    if (tid < 16) {
        float s;
        if (es_s[tid] > 0.f) {
            s = ws[WS_S1];
            for (int m = 0; m < 128; ++m) s += ws[WS_W2 + m] * avg[tid*128 + m];
        } else {
            s = ws[WS_S0];
        }
        s_sh[tid] = s * scale;
    }
    __syncthreads();
    if (tid == 0) {
        float mx = -1e30f;
        #pragma unroll
        for (int c = 0; c < 16; ++c) mx = fmaxf(mx, s_sh[c]);
        float e[16]; float den = 0.f;
        #pragma unroll
        for (int c = 0; c < 16; ++c) { e[c] = __expf(s_sh[c] - mx); den += e[c]; }
        float a = 0.f;
        #pragma unroll
        for (int c = 0; c < 16; ++c) {
            const float g = e[c] / den;
            gw_s[c] = g;
            if (es_s[c] > 0.f) a += g;
        }
        alpha_s = a;
    }
    __syncthreads();
    {
        float a = 0.f;
        #pragma unroll
        for (int c = 0; c < 16; ++c) a += gw_s[c] * avg[c*128 + tid];
        mavg[tid] = a;
    }
    __syncthreads();
    const float alpha = alpha_s;
    {   // t = Wv mavg + alpha*bv
        float a = alpha * bv[tid];
        const float4* w = (const float4*)(Wv + tid*128);
        const float4* v = (const float4*)mavg;
        #pragma unroll
        for (int m = 0; m < 32; ++m) { float4 ww = w[m], vv = v[m];
            a += ww.x*vv.x + ww.y*vv.y + ww.z*vv.z + ww.w*vv.w; }
        t_s[tid] = a;
    }
    __syncthreads();
    {   // mix = Wo t + alpha*bo
        float a = alpha * bo[tid];
        const float4* w = (const float4*)(Wo + tid*128);
        const float4* v = (const float4*)t_s;
        #pragma unroll
        for (int m = 0; m < 32; ++m) { float4 ww = w[m], vv = v[m];
            a += ww.x*vv.x + ww.y*vv.y + ww.z*vv.z + ww.w*vv.w; }
        mix[tid] = a;
    }
    __syncthreads();
    {   // ctx = Wgv mix + bgv ; combined = h + ctx
        float a = bgv[tid];
        const float4* w = (const float4*)(Wgv + tid*128);
        const float4* v = (const float4*)mix;
        #pragma unroll
        for (int m = 0; m < 32; ++m) { float4 ww = w[m], vv = v[m];
            a += ww.x*vv.x + ww.y*vv.y + ww.z*vv.z + ww.w*vv.w; }
        comb[tid] = ws[WS_H + tid] + a;
    }
    __syncthreads();
    if (tid < 2) {
        float a = bc[tid];
        for (int m = 0; m < 128; ++m) a += Wc[tid*128 + m] * comb[m];
        out[tid] = a;
    }
}

extern "C" void kernel_launch(void* const* d_in, const int* in_sizes, int n_in,
                              void* d_out, int out_size, void* d_ws, size_t ws_size,
                              hipStream_t stream) {
    (void)in_sizes; (void)n_in; (void)out_size; (void)ws_size;
    const float* target = (const float*)d_in[0];
    const float* others = (const float*)d_in[1];
    const int*   mask   = (const int*)d_in[2];
    const float* W_ih = (const float*)d_in[3];
    const float* W_hh = (const float*)d_in[4];
    const float* b_ih = (const float*)d_in[5];
    const float* b_hh = (const float*)d_in[6];
    const float* Wq  = (const float*)d_in[7];  const float* bq  = (const float*)d_in[8];
    const float* Wk  = (const float*)d_in[9];  const float* bk  = (const float*)d_in[10];
    const float* Wv  = (const float*)d_in[11]; const float* bv  = (const float*)d_in[12];
    const float* Wo  = (const float*)d_in[13]; const float* bo  = (const float*)d_in[14];
    const float* Wgq = (const float*)d_in[15]; const float* bgq = (const float*)d_in[16];
    const float* Wgk = (const float*)d_in[17]; const float* bgk = (const float*)d_in[18];
    const float* Wgv = (const float*)d_in[19]; const float* bgv = (const float*)d_in[20];
    const float* Wc  = (const float*)d_in[21]; const float* bc  = (const float*)d_in[22];
    float* ws  = (float*)d_ws;
    float* out = (float*)d_out;

    k0_prefetch<<<dim3(256), dim3(256), 0, stream>>>(W_ih, W_hh, Wq, Wk, Wv, Wo,
        Wgq, Wgk, Wgv, Wc, ws);
    k1_target<<<dim3(1), dim3(512), 0, stream>>>(target, W_ih, W_hh, b_ih, b_hh,
        Wq, bq, Wk, bk, Wv, bv, Wo, bo, Wgq, bgq, Wgk, bgk, ws);
    k3_neighbors<<<dim3(K3_BLOCKS), dim3(256), 0, stream>>>(target, others, mask,
        W_ih, b_ih, b_hh, ws);
    k4_finale<<<dim3(1), dim3(128), 0, stream>>>(Wv, bv, Wo, bo, Wgv, bgv, Wc, bc, ws, out);
}

// Round 5
// 167.397 us; speedup vs baseline: 1.1294x; 1.1294x over previous
//
#include <hip/hip_runtime.h>
#include <math.h>

// ---- problem constants ----
#define NH 16384
#define HDIM 128

// ---- ws layout (float offsets) ----
#define WS_H     0
#define WS_U     128
#define WS_W2    256
#define WS_QBK   384
#define WS_S0    385
#define WS_S1    386
#define WS_GUARD 400
#define WS_CELL  512            // 16384 ints (reinterpreted)
#define WS_ACCR  17408          // NREP * 2064 floats
#define REP_STRIDE 2064
#define NREP 16
#define WS_HO    65536          // 16384 * 128 floats (8 MB)

__device__ __forceinline__ float frcp_(float x){ return __builtin_amdgcn_rcpf(x); }
__device__ __forceinline__ float fsig_(float x){ return frcp_(1.f + __expf(-x)); }
__device__ __forceinline__ float ftanh_(float x){ return 1.f - 2.f*frcp_(1.f + __expf(2.f*x)); }

// ================= K_I: fused target-LSTM (block 0) + neighbor ho (blocks 1..256) ==========
__global__ __launch_bounds__(512, 2) void kI_fused(
    const float* __restrict__ target, const float* __restrict__ others,
    const int* __restrict__ mask,
    const float* __restrict__ W_ih, const float* __restrict__ W_hh,
    const float* __restrict__ b_ih, const float* __restrict__ b_hh,
    const float* __restrict__ Wq,  const float* __restrict__ bq,
    const float* __restrict__ Wk,  const float* __restrict__ bk,
    const float* __restrict__ Wv,  const float* __restrict__ bv,
    const float* __restrict__ Wo,  const float* __restrict__ bo,
    const float* __restrict__ Wgq, const float* __restrict__ bgq,
    const float* __restrict__ Wgk, const float* __restrict__ bgk,
    const float* __restrict__ Wgv,
    float* __restrict__ ws)
{
    const int tid = threadIdx.x;
    const int bid = blockIdx.x;

    if (bid != 0) {
        // ---------------- neighbor path ----------------
        __shared__ float xs[64*8];
        const int nb = bid - 1;              // 0..255
        const int n0 = nb * 64;
        const float* __restrict__ oth = others + 14*NH*8;

        // zero the global accumulator replicas (blocks 1..16)
        if (nb < NREP) {
            float* g = ws + WS_ACCR + nb*REP_STRIDE;
            for (int i = tid; i < REP_STRIDE; i += 512) g[i] = 0.f;
        }
        // XCD-sibling prefetch of block-0 tail matrices (heuristic: bid%8==0 shares XCD 0)
        if ((bid & 7) == 0) {
            const int m = (bid >> 3) - 1;    // bid=8..56 -> 0..6
            if (m < 7) {
                const float* M = (m==0)?Wq:(m==1)?Wk:(m==2)?Wgq:(m==3)?Wgk:(m==4)?Wo:(m==5)?Wv:Wgv;
                const float4* p4 = (const float4*)M;
                float a = 0.f;
                for (int i = tid; i < 4096; i += 512) { float4 v = p4[i]; a += v.x+v.y+v.z+v.w; }
                if (a == 1.0e38f) ws[WS_GUARD] = a;   // never true; keeps loads live
            }
        }

        for (int i = tid; i < 512; i += 512) xs[i] = oth[n0*8 + i];

        const int d = tid & 127;
        const int sub = tid >> 7;            // 0..3
        float wi[8], wg[8], wo[8];
        #pragma unroll
        for (int k = 0; k < 8; ++k) {
            wi[k] = W_ih[d*8 + k];
            wg[k] = W_ih[(256+d)*8 + k];
            wo[k] = W_ih[(384+d)*8 + k];
        }
        const float bi  = b_ih[d]     + b_hh[d];
        const float bg  = b_ih[256+d] + b_hh[256+d];
        const float bo_ = b_ih[384+d] + b_hh[384+d];
        __syncthreads();

        if (tid < 64) {
            const int n = n0 + tid;
            const float tx0 = target[14*8 + 0], tx1 = target[14*8 + 1];
            const float r0 = xs[tid*8]     - tx0;
            const float r1 = xs[tid*8 + 1] - tx1;
            bool ok = (fabsf(r0) <= 2.f) & (fabsf(r1) <= 2.f) & (mask[14*NH + n] != 0);
            const int cx = (int)truncf(r0) + 2;
            const int cy = (int)truncf(r1) + 2;
            ok = ok & (cx >= 0) & (cx < 4) & (cy >= 0) & (cy < 4);
            ((int*)(ws + WS_CELL))[n] = ok ? (cy*4 + cx) : -1;
        }

        float* __restrict__ hoq = ws + WS_HO;
        #pragma unroll 4
        for (int p = 0; p < 16; ++p) {
            const int j = sub + 4*p;         // 0..63
            const float* x = &xs[j*8];
            float gi = bi, gg = bg, go = bo_;
            #pragma unroll
            for (int k = 0; k < 8; ++k) { gi += x[k]*wi[k]; gg += x[k]*wg[k]; go += x[k]*wo[k]; }
            const float ho = fsig_(go) * ftanh_(fsig_(gi) * ftanh_(gg));
            hoq[(n0 + j)*128 + d] = ho;
        }
        return;
    }

    // ---------------- block 0: serial target LSTM + folded precomputes ----------------
    __shared__ __align__(16) float h_s[128];
    __shared__ float g_s[512];
    __shared__ float red[512];
    __shared__ __align__(16) float qq_s[256];
    __shared__ __align__(16) float u_s[128], ug_s[128], w1_s[128], w2_s[128];
    if (tid < 128) h_s[tid] = 0.f;

    float wih[8];
    #pragma unroll
    for (int k = 0; k < 8; ++k) wih[k] = W_ih[tid*8 + k];
    const float bsum = b_ih[tid] + b_hh[tid];
    float4 whh[32];
    {
        const float4* w4 = (const float4*)(W_hh + tid*128);
        #pragma unroll
        for (int m = 0; m < 32; ++m) whh[m] = w4[m];
    }
    float c = 0.f;
    __syncthreads();

    for (int t = 0; t < 15; ++t) {
        float g = bsum;
        #pragma unroll
        for (int k = 0; k < 8; ++k) g += target[t*8 + k] * wih[k];
        const float4* h4 = (const float4*)h_s;
        float a0 = 0.f, a1 = 0.f, a2 = 0.f, a3 = 0.f;
        #pragma unroll
        for (int m = 0; m < 32; m += 4) {
            float4 x0 = h4[m], x1 = h4[m+1], x2 = h4[m+2], x3 = h4[m+3];
            a0 += whh[m  ].x*x0.x + whh[m  ].y*x0.y + whh[m  ].z*x0.z + whh[m  ].w*x0.w;
            a1 += whh[m+1].x*x1.x + whh[m+1].y*x1.y + whh[m+1].z*x1.z + whh[m+1].w*x1.w;
            a2 += whh[m+2].x*x2.x + whh[m+2].y*x2.y + whh[m+2].z*x2.z + whh[m+2].w*x2.w;
            a3 += whh[m+3].x*x3.x + whh[m+3].y*x3.y + whh[m+3].z*x3.z + whh[m+3].w*x3.w;
        }
        g += (a0 + a1) + (a2 + a3);
        g_s[tid] = g;
        __syncthreads();
        if (tid < 128) {
            float ig = fsig_(g_s[tid]);
            float fg = fsig_(g_s[tid+128]);
            float gg = ftanh_(g_s[tid+256]);
            float og = fsig_(g_s[tid+384]);
            c = fg*c + ig*gg;
            h_s[tid] = og*ftanh_(c);
        }
        __syncthreads();
    }

    // phase A: q | qg (2-way j-split over 512 threads)
    {
        const int o = tid & 255, p = tid >> 8;
        const float* Wrow = (o < 128) ? (Wq + o*128) : (Wgq + (o & 127)*128);
        const float4* w4 = (const float4*)Wrow + p*16;
        const float4* h4 = (const float4*)h_s + p*16;
        float a = 0.f;
        #pragma unroll
        for (int m = 0; m < 16; ++m) { float4 w = w4[m], v = h4[m];
            a += w.x*v.x + w.y*v.y + w.z*v.z + w.w*v.w; }
        red[tid] = a;
    }
    __syncthreads();
    if (tid < 256) qq_s[tid] = red[tid] + red[tid+256] + ((tid < 128) ? bq[tid] : bgq[tid & 127]);
    __syncthreads();
    // phase B: u = Wk^T q | ug = Wgk^T qg
    {
        const int o = tid & 255, p = tid >> 8;
        const int a_ = o & 127;
        const float* W = (o < 128) ? Wk : Wgk;
        const int qb = (o < 128) ? 0 : 128;
        float a = 0.f;
        #pragma unroll 8
        for (int j = p*64; j < p*64 + 64; ++j) a += qq_s[qb + j] * W[j*128 + a_];
        red[tid] = a;
    }
    __syncthreads();
    if (tid < 256) {
        float v = red[tid] + red[tid+256];
        if (tid < 128) u_s[tid] = v; else ug_s[tid & 127] = v;
    }
    __syncthreads();
    // phase C: w1 = Wo^T ug
    {
        const int o = tid & 127, p = tid >> 7;
        float a = 0.f;
        #pragma unroll 8
        for (int j = p*32; j < p*32 + 32; ++j) a += ug_s[j] * Wo[j*128 + o];
        red[tid] = a;
    }
    __syncthreads();
    if (tid < 128) w1_s[tid] = red[tid] + red[tid+128] + red[tid+256] + red[tid+384];
    __syncthreads();
    // phase D: w2 = Wv^T w1
    {
        const int o = tid & 127, p = tid >> 7;
        float a = 0.f;
        #pragma unroll 8
        for (int j = p*32; j < p*32 + 32; ++j) a += w1_s[j] * Wv[j*128 + o];
        red[tid] = a;
    }
    __syncthreads();
    if (tid < 128) w2_s[tid] = red[tid] + red[tid+128] + red[tid+256] + red[tid+384];
    __syncthreads();
    if (tid < 128) {
        red[tid]     = qq_s[tid] * bk[tid];
        red[128+tid] = qq_s[128+tid] * bgk[tid];
        red[256+tid] = w1_s[tid]*bv[tid] + ug_s[tid]*bo[tid];
    }
    __syncthreads();
    if (tid == 0) {
        float qbk = 0.f, s0 = 0.f, sx = 0.f;
        for (int j = 0; j < 128; ++j) { qbk += red[j]; s0 += red[128+j]; sx += red[256+j]; }
        ws[WS_QBK] = qbk; ws[WS_S0] = s0; ws[WS_S1] = sx + s0;
    }
    if (tid < 128) {
        ws[WS_H + tid]  = h_s[tid];
        ws[WS_U + tid]  = u_s[tid];
        ws[WS_W2 + tid] = w2_s[tid];
    }
}

// ================= K_II: scores + per-cell weighted accumulation ==========
__global__ __launch_bounds__(256) void kII_accum(float* __restrict__ ws)
{
    __shared__ float acc[REP_STRIDE];          // [16][128] + 16 esums
    const int tid  = threadIdx.x;
    const int lane = tid & 63;
    const int wv   = tid >> 6;                 // 0..3

    for (int i = tid; i < REP_STRIDE; i += 256) acc[i] = 0.f;

    const float u0 = ws[WS_U + lane];
    const float u1 = ws[WS_U + 64 + lane];
    const float qbk = ws[WS_QBK];
    const float scale = 0.08838834764831845f;  // 1/sqrt(128)
    const float* __restrict__ hoq = ws + WS_HO;
    const int* __restrict__ cellw = (const int*)(ws + WS_CELL);
    __syncthreads();

    const int n0 = blockIdx.x*64 + wv*16;
    #pragma unroll 2
    for (int i = 0; i < 16; ++i) {
        const int n = n0 + i;
        const int cw = cellw[n];
        const float h0 = hoq[n*128 + lane];
        const float h1 = hoq[n*128 + 64 + lane];
        float p = u0*h0 + u1*h1;
        #pragma unroll
        for (int s = 1; s < 64; s <<= 1) p += __shfl_xor(p, s, 64);
        const float e = (cw >= 0) ? __expf((p + qbk) * scale) : 0.f;
        const int cell = (cw >= 0) ? cw : 0;
        atomicAdd(&acc[cell*128 + lane], e*h0);
        atomicAdd(&acc[cell*128 + 64 + lane], e*h1);
        if (lane == 0) atomicAdd(&acc[2048 + cell], e);
    }
    __syncthreads();
    float* g = ws + WS_ACCR + (blockIdx.x & (NREP-1))*REP_STRIDE;
    for (int i = tid; i < REP_STRIDE; i += 256) {
        const float v = acc[i];
        if (v != 0.f) atomicAdd(&g[i], v);
    }
}

// ================= K_III: finale ==========
__global__ __launch_bounds__(256) void kIII_finale(
    const float* __restrict__ Wv, const float* __restrict__ bv,
    const float* __restrict__ Wo, const float* __restrict__ bo,
    const float* __restrict__ Wgv, const float* __restrict__ bgv,
    const float* __restrict__ Wc, const float* __restrict__ bc,
    const float* __restrict__ ws, float* __restrict__ out)
{
    __shared__ __align__(16) float avg[2048];
    __shared__ float es_s[16], gw_s[16], s_sh[16];
    __shared__ __align__(16) float mavg[128], t_s[128], mix[128], comb[128];
    __shared__ float alpha_s;
    const int tid = threadIdx.x;
    const float scale = 0.08838834764831845f;

    if (tid < 16) {
        float e = 0.f;
        #pragma unroll
        for (int r = 0; r < NREP; ++r) e += ws[WS_ACCR + r*REP_STRIDE + 2048 + tid];
        es_s[tid] = e;
    }
    __syncthreads();
    for (int i = tid; i < 2048; i += 256) {
        float a = 0.f;
        #pragma unroll
        for (int r = 0; r < NREP; ++r) a += ws[WS_ACCR + r*REP_STRIDE + i];
        const float es = es_s[i >> 7];
        avg[i] = (es > 0.f) ? a / es : 0.f;
    }
    __syncthreads();
    // per-cell score: 8 lanes per cell
    if (tid < 128) {
        const int c = tid >> 3, j = tid & 7;
        float a = 0.f;
        #pragma unroll
        for (int k = 0; k < 16; ++k) {
            const int d = j + 8*k;
            a += ws[WS_W2 + d] * avg[c*128 + d];
        }
        #pragma unroll
        for (int s = 1; s < 8; s <<= 1) a += __shfl_xor(a, s, 64);
        if (j == 0)
            s_sh[c] = ((es_s[c] > 0.f) ? (ws[WS_S1] + a) : ws[WS_S0]) * scale;
    }
    __syncthreads();
    if (tid == 0) {
        float mx = -1e30f;
        #pragma unroll
        for (int c = 0; c < 16; ++c) mx = fmaxf(mx, s_sh[c]);
        float e[16]; float den = 0.f;
        #pragma unroll
        for (int c = 0; c < 16; ++c) { e[c] = __expf(s_sh[c] - mx); den += e[c]; }
        float a = 0.f;
        #pragma unroll
        for (int c = 0; c < 16; ++c) {
            const float g = e[c] / den;
            gw_s[c] = g;
            if (es_s[c] > 0.f) a += g;
        }
        alpha_s = a;
    }
    __syncthreads();
    if (tid < 128) {
        float a = 0.f;
        #pragma unroll
        for (int c = 0; c < 16; ++c) a += gw_s[c] * avg[c*128 + tid];
        mavg[tid] = a;
    }
    __syncthreads();
    const float alpha = alpha_s;
    if (tid < 128) {   // t = Wv mavg + alpha*bv
        float a = alpha * bv[tid];
        const float4* w = (const float4*)(Wv + tid*128);
        const float4* v = (const float4*)mavg;
        #pragma unroll
        for (int m = 0; m < 32; ++m) { float4 ww = w[m], vv = v[m];
            a += ww.x*vv.x + ww.y*vv.y + ww.z*vv.z + ww.w*vv.w; }
        t_s[tid] = a;
    }
    __syncthreads();
    if (tid < 128) {   // mix = Wo t + alpha*bo
        float a = alpha * bo[tid];
        const float4* w = (const float4*)(Wo + tid*128);
        const float4* v = (const float4*)t_s;
        #pragma unroll
        for (int m = 0; m < 32; ++m) { float4 ww = w[m], vv = v[m];
            a += ww.x*vv.x + ww.y*vv.y + ww.z*vv.z + ww.w*vv.w; }
        mix[tid] = a;
    }
    __syncthreads();
    if (tid < 128) {   // comb = h + Wgv mix + bgv
        float a = bgv[tid];
        const float4* w = (const float4*)(Wgv + tid*128);
        const float4* v = (const float4*)mix;
        #pragma unroll
        for (int m = 0; m < 32; ++m) { float4 ww = w[m], vv = v[m];
            a += ww.x*vv.x + ww.y*vv.y + ww.z*vv.z + ww.w*vv.w; }
        comb[tid] = ws[WS_H + tid] + a;
    }
    __syncthreads();
    if (tid < 2) {
        float a = bc[tid];
        for (int m = 0; m < 128; ++m) a += Wc[tid*128 + m] * comb[m];
        out[tid] = a;
    }
}

extern "C" void kernel_launch(void* const* d_in, const int* in_sizes, int n_in,
                              void* d_out, int out_size, void* d_ws, size_t ws_size,
                              hipStream_t stream) {
    (void)in_sizes; (void)n_in; (void)out_size; (void)ws_size;
    const float* target = (const float*)d_in[0];
    const float* others = (const float*)d_in[1];
    const int*   mask   = (const int*)d_in[2];
    const float* W_ih = (const float*)d_in[3];
    const float* W_hh = (const float*)d_in[4];
    const float* b_ih = (const float*)d_in[5];
    const float* b_hh = (const float*)d_in[6];
    const float* Wq  = (const float*)d_in[7];  const float* bq  = (const float*)d_in[8];
    const float* Wk  = (const float*)d_in[9];  const float* bk  = (const float*)d_in[10];
    const float* Wv  = (const float*)d_in[11]; const float* bv  = (const float*)d_in[12];
    const float* Wo  = (const float*)d_in[13]; const float* bo  = (const float*)d_in[14];
    const float* Wgq = (const float*)d_in[15]; const float* bgq = (const float*)d_in[16];
    const float* Wgk = (const float*)d_in[17]; const float* bgk = (const float*)d_in[18];
    const float* Wgv = (const float*)d_in[19]; const float* bgv = (const float*)d_in[20];
    const float* Wc  = (const float*)d_in[21]; const float* bc  = (const float*)d_in[22];
    float* ws  = (float*)d_ws;
    float* out = (float*)d_out;

    kI_fused<<<dim3(257), dim3(512), 0, stream>>>(target, others, mask,
        W_ih, W_hh, b_ih, b_hh, Wq, bq, Wk, bk, Wv, bv, Wo, bo,
        Wgq, bgq, Wgk, bgk, Wgv, ws);
    kII_accum<<<dim3(256), dim3(256), 0, stream>>>(ws);
    kIII_finale<<<dim3(1), dim3(256), 0, stream>>>(Wv, bv, Wo, bo, Wgv, bgv,
        Wc, bc, ws, out);
}